// Round 6
// baseline (215.018 us; speedup 1.0000x reference)
//
#include <hip/hip_runtime.h>
#include <hip/hip_bf16.h>
#include <stdint.h>

// Conv2d: x[128][256][256] f32, w[256][128][3][3] f32, bias[256] f32 ->
// out[256][256][256] f32. pad=1 stride=1. bf16 MFMA implicit GEMM.
// R6 = measured-wins composition:
//  - R2 staging (plain uint4 loads + ds_write; global_load_lds bypasses
//    L2/L3 per R5 FETCH 38.6->103.8 MB — never again for reused data)
//  - R5 swizzled LDS layout (0 bank conflicts measured)
//  - register prefetch across the barrier (staging latency off critical path)
//  - 1-ahead A-tap software pipeline
//  - grid (2,512): m-half fastest -> paired blocks co-fetch xp rows
//   ws: x_p bf16 [258][258][128] = 17,040,384 B ; W_pk bf16 [9][256][128]

#define CIN   128
#define COUT  256
#define HH    256
#define WW    256
#define WP    258
#define XP_ELEMS (258 * 258 * 128)

// LDS buffer: 3 rows x 130 cols x 4 slots of 16B = 1560 chunks = 24,960 B
// chunk (r,c,slot) at index (r*130+c)*4+slot ; slot holds icg=(slot-(c>>1))&3
#define CHUNKS 1560
#define ROW_SH 4160              // shorts per r-row: 130*4*8

typedef __attribute__((ext_vector_type(8))) __bf16 bf16x8;
typedef __attribute__((ext_vector_type(4))) float  floatx4;

// ---------------- prep 1: zero the padded border ----------------
__global__ __launch_bounds__(256) void zero_border(unsigned short* __restrict__ xp) {
    int id = blockIdx.x * 256 + threadIdx.x;
    if (id >= 1028 * 16) return;
    int p = id >> 4, icg = id & 15;
    int hp, wp;
    if (p < 258)      { hp = 0;   wp = p; }
    else if (p < 516) { hp = 257; wp = p - 258; }
    else { int s = p - 516; hp = 1 + (s >> 1); wp = (s & 1) * 257; }
    uint4 z = {0u, 0u, 0u, 0u};
    *(uint4*)(xp + ((size_t)hp * WP + wp) * CIN + icg * 8) = z;
}

// ---------------- prep 2: transpose+cast x[c][h][w] -> xp[h+1][w+1][c] ----------------
__global__ __launch_bounds__(256) void xpose_pad(const float* __restrict__ x,
                                                 unsigned short* __restrict__ xp) {
    int h  = blockIdx.x;
    int w0 = blockIdx.y << 4;
    int wq  = threadIdx.x & 15;
    int icg = threadIdx.x >> 4;
    const float* src = x + (size_t)(icg * 8) * (HH * WW) + h * WW + w0 + wq;
    union { unsigned short s[8]; uint4 v; } u;
#pragma unroll
    for (int j = 0; j < 8; ++j) {
        __hip_bfloat16 b = __float2bfloat16(src[(size_t)j * (HH * WW)]);
        u.s[j] = __builtin_bit_cast(unsigned short, b);
    }
    *(uint4*)(xp + ((size_t)(h + 1) * WP + (w0 + wq + 1)) * CIN + icg * 8) = u.v;
}

// ---------------- prep 3: pack weights -> bf16 W_pk[kk][o][ic] ----------------
__global__ __launch_bounds__(256) void wpack(const float* __restrict__ w,
                                             unsigned short* __restrict__ wp) {
    int rem = blockIdx.x * 256 + threadIdx.x;   // o*128+ic
    const float* src = w + (size_t)rem * 9;
#pragma unroll
    for (int kk = 0; kk < 9; ++kk) {
        __hip_bfloat16 b = __float2bfloat16(src[kk]);
        wp[(size_t)kk * (COUT * CIN) + rem] = __builtin_bit_cast(unsigned short, b);
    }
}

// ---------------- main conv ----------------
// 256 thr (4 waves, 2x2 wave tiles of 64x64), block tile 128m x 128n.
__global__ __launch_bounds__(256, 3) void conv_mfma(
    const unsigned short* __restrict__ xp,   // [258][258][128] bf16
    const unsigned short* __restrict__ wpk,  // [9][256][128]   bf16
    const float* __restrict__ bias,          // [256] f32
    float* __restrict__ out) {               // [256][65536] f32
    __shared__ __align__(16) unsigned short x_lds[CHUNKS * 8];   // 24,960 B

    const int tid  = threadIdx.x;
    const int lane = tid & 63;
    const int wv   = tid >> 6;
    const int l15  = lane & 15;
    const int lg   = lane >> 4;
    const int m0   = blockIdx.x << 7;        // m-half: fastest grid dim
    const int h    = blockIdx.y >> 1;
    const int w0   = (blockIdx.y & 1) << 7;
    const int wave_m = (wv >> 1) << 6;
    const int wave_n = (wv & 1) << 6;

    // staging decode: chunk s -> (r, c, slot) -> global offset (ic0 added later)
    int goff[6];
#pragma unroll
    for (int k = 0; k < 6; ++k) {
        int s = k * 256 + tid;
        int r = s / 520, t = s - r * 520;
        int c = t >> 2, slot = t & 3;
        int icg = (slot - (c >> 1)) & 3;
        goff[k] = ((h + r) * WP + w0 + c) * CIN + icg * 8;
    }
    const bool hrem = tid < 24;              // 1560 - 1536 remainder chunks
    int grem = 0;
    if (hrem) {
        int s = 1536 + tid;
        int r = s / 520, t = s - r * 520;
        int c = t >> 2, slot = t & 3;
        int icg = (slot - (c >> 1)) & 3;
        grem = ((h + r) * WP + w0 + c) * CIN + icg * 8;
    }

    // B-frag LDS short-offsets (r-term added per tap); icg read back = lg
    int coff[3][4];
#pragma unroll
    for (int kw = 0; kw < 3; ++kw)
#pragma unroll
        for (int fj = 0; fj < 4; ++fj) {
            int c = wave_n + fj * 16 + l15 + kw;
            coff[kw][fj] = (c * 4 + ((lg + (c >> 1)) & 3)) * 8;
        }

    const unsigned short* abase = wpk + (size_t)(m0 + wave_m + l15) * CIN + lg * 8;

    floatx4 acc[4][4];
#pragma unroll
    for (int fi = 0; fi < 4; ++fi)
#pragma unroll
        for (int fj = 0; fj < 4; ++fj) {
            floatx4 z = {0.f, 0.f, 0.f, 0.f};
            acc[fi][fj] = z;
        }

    // prologue: prefetch staging for ic0=0 and A-frags for tap 0
    uint4 pf[6], pfr;
#pragma unroll
    for (int k = 0; k < 6; ++k) pf[k] = *(const uint4*)(xp + goff[k]);
    if (hrem) pfr = *(const uint4*)(xp + grem);

    bf16x8 a0[4];
#pragma unroll
    for (int fi = 0; fi < 4; ++fi)
        a0[fi] = *(const bf16x8*)(abase + fi * 2048);          // tap0, ic0=0

    for (int it = 0; it < 4; ++it) {
        const int ic0 = it * 32;
        __syncthreads();                     // prev iter's ds_reads complete
#pragma unroll
        for (int k = 0; k < 6; ++k)
            *(uint4*)(x_lds + (size_t)(k * 256 + tid) * 8) = pf[k];
        if (hrem) *(uint4*)(x_lds + (size_t)(1536 + tid) * 8) = pfr;
        __syncthreads();                     // writes visible
        if (it < 3) {                        // prefetch next K-block during compute
#pragma unroll
            for (int k = 0; k < 6; ++k)
                pf[k] = *(const uint4*)(xp + goff[k] + ic0 + 32);
            if (hrem) pfr = *(const uint4*)(xp + grem + ic0 + 32);
        }

#pragma unroll
        for (int kk = 0; kk < 9; ++kk) {
            const int kh = kk / 3, kw = kk - kh * 3;
            // prefetch A for tap kk+1 (wraps into next ic-block; clamped dummy at end)
            const int kk1 = (kk == 8) ? 0 : kk + 1;
            int icn = (kk == 8) ? ic0 + 32 : ic0;
            if (icn > 96) icn = 96;
            bf16x8 an[4];
#pragma unroll
            for (int fi = 0; fi < 4; ++fi)
                an[fi] = *(const bf16x8*)(abase + (size_t)kk1 * 32768 + fi * 2048 + icn);

            bf16x8 b[4];
#pragma unroll
            for (int fj = 0; fj < 4; ++fj)
                b[fj] = *(const bf16x8*)(x_lds + kh * ROW_SH + coff[kw][fj]);

#pragma unroll
            for (int fi = 0; fi < 4; ++fi)
#pragma unroll
                for (int fj = 0; fj < 4; ++fj)
                    acc[fi][fj] = __builtin_amdgcn_mfma_f32_16x16x32_bf16(
                        a0[fi], b[fj], acc[fi][fj], 0, 0, 0);
#pragma unroll
            for (int fi = 0; fi < 4; ++fi) a0[fi] = an[fi];
        }
    }

    // epilogue: D col=lane&15, row=(lane>>4)*4+reg
    const int nb = h * WW + w0 + wave_n + l15;
#pragma unroll
    for (int fi = 0; fi < 4; ++fi) {
        int row0 = m0 + wave_m + fi * 16 + lg * 4;
#pragma unroll
        for (int r = 0; r < 4; ++r) {
            float bv = bias[row0 + r];
#pragma unroll
            for (int fj = 0; fj < 4; ++fj)
                out[(size_t)(row0 + r) * (HH * WW) + nb + fj * 16] = acc[fi][fj][r] + bv;
        }
    }
}

extern "C" void kernel_launch(void* const* d_in, const int* in_sizes, int n_in,
                              void* d_out, int out_size, void* d_ws, size_t ws_size,
                              hipStream_t stream) {
    (void)in_sizes; (void)n_in; (void)out_size; (void)ws_size;
    const float* x    = (const float*)d_in[0];
    const float* w    = (const float*)d_in[1];
    const float* bias = (const float*)d_in[2];
    float* out = (float*)d_out;

    unsigned short* xp  = (unsigned short*)d_ws;
    unsigned short* wpk = xp + XP_ELEMS;

    zero_border<<<dim3(65), dim3(256), 0, stream>>>(xp);
    xpose_pad<<<dim3(256, 16), dim3(256), 0, stream>>>(x, xp);
    wpack<<<dim3(128), dim3(256), 0, stream>>>(w, wpk);
    conv_mfma<<<dim3(2, 512), dim3(256), 0, stream>>>(xp, wpk, bias, out);
}